// Round 7
// baseline (132.993 us; speedup 1.0000x reference)
//
#include <hip/hip_runtime.h>
#include <hip/hip_bf16.h>
#include <math.h>

// out[b,i,p] = sqrt(yr^2+yi^2); yr/yi = (Hr/Hi[b] @ x[b])*scale + noise*0.01
// B=32, C=256, P=3136. Memory-bound (~298MB HBM observed -> ~47us floor).
// Round-7: zero-barrier K-loop. x staged full-K once (64KB LDS, one sync);
// H A-frags read directly from the PERMUTED bf16 ws (dense 16B/lane, L2-hot),
// register-double-buffered one K-step ahead. Noise+magnitude in epilogue
// (desynced waves overlap it with other waves' K-loops).

#define NBATCH 32
#define NC 256
#define NP 3136
#define BM 128
#define BN 64
#define BK 32
#define NBN 49
#define NKI 8          // 256/32 K-steps

typedef __attribute__((ext_vector_type(8))) short short8;
typedef __attribute__((ext_vector_type(4))) float f32x4;

static __device__ __forceinline__ void gload16(const void* g, void* l) {
  __builtin_amdgcn_global_load_lds(
      (const __attribute__((address_space(1))) void*)g,
      (__attribute__((address_space(3))) void*)l, 16, 0, 0);
}

static __device__ __forceinline__ unsigned short bfr(float f) {
  __hip_bfloat16 h = __float2bfloat16(f);   // RNE; pairs into v_cvt_pk_bf16_f32
  return *reinterpret_cast<unsigned short*>(&h);
}

// ---- pre-pass: permute Hr/Hi fp32 -> bf16 ws in fragment-image layout ----
// ws elem idx: (((b2m*8 + kt)*2 + plane)*4096) + fq*1024 + row*8 + e
//   b2m=b*2+bm, kt=K-tile, plane 0=r/1=i, fq=k-chunk, row=M-row in 128-tile.
__global__ __launch_bounds__(256)
void perm_h_kernel(const float* __restrict__ hr, const float* __restrict__ hi,
                   unsigned short* __restrict__ ws)
{
  const int blk   = blockIdx.x;        // b2m*8 + kt  (512 blocks)
  const int kt    = blk & 7;
  const int b2m   = blk >> 3;
  const int plane = threadIdx.x >> 7;  // 0..1
  const int row   = threadIdx.x & 127; // 0..127
  const int b     = b2m >> 1;
  const int bm    = b2m & 1;

  const float* src = (plane ? hi : hr)
      + ((size_t)b * NC + bm * 128 + row) * NC + kt * 32;
  unsigned short* dst = ws + ((size_t)(b2m * 8 + kt) * 2 + plane) * 4096 + row * 8;

  #pragma unroll
  for (int fq = 0; fq < 4; ++fq) {
    const float4 v0 = *reinterpret_cast<const float4*>(src + fq * 8);
    const float4 v1 = *reinterpret_cast<const float4*>(src + fq * 8 + 4);
    union { uint4 v; unsigned short u[8]; } o;
    o.u[0] = bfr(v0.x); o.u[1] = bfr(v0.y); o.u[2] = bfr(v0.z); o.u[3] = bfr(v0.w);
    o.u[4] = bfr(v1.x); o.u[5] = bfr(v1.y); o.u[6] = bfr(v1.z); o.u[7] = bfr(v1.w);
    *reinterpret_cast<uint4*>(dst + fq * 1024) = o.v;
  }
}

// x LDS: fp32 [k 0..255][p 0..63], phys 16B-chunk = logical ^ swz((k>>3)&3)
// (0 bank conflicts verified r2-r6; note (k>>3)&3 == fq for k = t*32+fq*8+j).
template<int PRE>
__global__ __launch_bounds__(512, 4)
void rayleigh_main(const float* __restrict__ xg,
                   const float* __restrict__ Hrg,
                   const float* __restrict__ Hig,
                   const unsigned short* __restrict__ Hperm,
                   const float* __restrict__ nrg,
                   const float* __restrict__ nig,
                   float* __restrict__ outg)
{
  __shared__ float x_lds[NC * BN];               // 64 KB, full K

  // XCD-chunked bijection: 3136 = 8*392. Each XCD owns 4 whole batches.
  const int raw = blockIdx.x;
  const int v   = (raw & 7) * 392 + (raw >> 3);
  const int b   = v / 98;
  const int r2  = v - b * 98;
  const int bm  = r2 / 49;
  const int bn  = r2 - bm * 49;

  const int tid  = threadIdx.x;
  const int lane = tid & 63;
  const int wave = tid >> 6;      // 8 waves: 2(M) x 4(N)
  const int wm   = wave >> 2;
  const int wn   = wave & 3;
  const int fr   = lane & 15;
  const int fq   = lane >> 4;

  const float* xsrc = xg + (size_t)b * NC * NP + (size_t)bn * BN;
  const size_t hrowbase = (size_t)b * NC + bm * BM;
  const size_t hpbase   = (size_t)((b * 2 + bm) * 8);

  // ---- stage x full-K: 4096 16B chunks, 8 DMA instr/wave, dense rows ----
  #pragma unroll
  for (int i = 0; i < 8; ++i) {
    const int C16 = (i * 8 + wave) * 64 + lane;
    const int k   = C16 >> 4;
    const int cp  = C16 & 15;
    const int fqk = (k >> 3) & 3;
    const int cl  = cp ^ (((fqk & 1) << 2) | (fqk >> 1));
    gload16(xsrc + (size_t)k * NP + cl * 4, (char*)x_lds + (i * 8 + wave) * 1024);
  }

  f32x4 accR[4], accI[4];
  #pragma unroll
  for (int m = 0; m < 4; ++m) {
    accR[m] = (f32x4){0.f, 0.f, 0.f, 0.f};
    accI[m] = (f32x4){0.f, 0.f, 0.f, 0.f};
  }

  const int xork = ((fq & 1) << 6) | ((fq >> 1) << 4);
  const int pcol = ((wn * 16 + fr) << 2) ^ xork;
  const int hfo  = fq * 1024 + (wm * 64 + fr) * 8;   // lane's frag offset

  // H fragment loader: dense 16B/lane from permuted ws (or fp32 orig if !PRE)
  auto loadH = [&](int t, short8 (&ar)[4], short8 (&ai)[4]) {
    #pragma unroll
    for (int m = 0; m < 4; ++m) {
      if constexpr (PRE) {
        const unsigned short* p = Hperm + ((hpbase + t) * 2) * 4096 + hfo + m * 128;
        ar[m] = *reinterpret_cast<const short8*>(p);
        ai[m] = *reinterpret_cast<const short8*>(p + 4096);
      } else {
        const float* p1 = Hrg + (hrowbase + wm * 64 + m * 16 + fr) * NC + t * 32 + fq * 8;
        const float* p2 = Hig + (hrowbase + wm * 64 + m * 16 + fr) * NC + t * 32 + fq * 8;
        const float4 v0 = *reinterpret_cast<const float4*>(p1);
        const float4 v1 = *reinterpret_cast<const float4*>(p1 + 4);
        const float4 w0 = *reinterpret_cast<const float4*>(p2);
        const float4 w1 = *reinterpret_cast<const float4*>(p2 + 4);
        union { short8 s; unsigned short u[8]; } a1, a2;
        a1.u[0] = bfr(v0.x); a1.u[1] = bfr(v0.y); a1.u[2] = bfr(v0.z); a1.u[3] = bfr(v0.w);
        a1.u[4] = bfr(v1.x); a1.u[5] = bfr(v1.y); a1.u[6] = bfr(v1.z); a1.u[7] = bfr(v1.w);
        a2.u[0] = bfr(w0.x); a2.u[1] = bfr(w0.y); a2.u[2] = bfr(w0.z); a2.u[3] = bfr(w0.w);
        a2.u[4] = bfr(w1.x); a2.u[5] = bfr(w1.y); a2.u[6] = bfr(w1.z); a2.u[7] = bfr(w1.w);
        ar[m] = a1.s; ai[m] = a2.s;
      }
    }
  };

  // one K-step: x frag from LDS (8 swizzled ds_read_b32 + pk-cvt), 8 MFMA
  auto step = [&](int t, short8 (&ar)[4], short8 (&ai)[4]) {
    union { short8 s; unsigned short u[8]; } u;
    #pragma unroll
    for (int j = 0; j < 8; ++j) {
      const float f = *reinterpret_cast<const float*>(
          (const char*)x_lds + ((t * 32 + fq * 8 + j) << 8) + pcol);
      u.u[j] = bfr(f);
    }
    const short8 xb = u.s;
    #pragma unroll
    for (int m = 0; m < 4; ++m) {
      accR[m] = __builtin_amdgcn_mfma_f32_16x16x32_bf16(ar[m], xb, accR[m], 0, 0, 0);
      accI[m] = __builtin_amdgcn_mfma_f32_16x16x32_bf16(ai[m], xb, accI[m], 0, 0, 0);
    }
  };

  short8 arA[4], aiA[4], arB[4], aiB[4];
  loadH(0, arA, aiA);           // in flight across the staging sync
  __syncthreads();              // x LDS ready (drains DMA + frag loads)

  // ---- zero-barrier K-loop, register-double-buffered H frags ----
  #pragma unroll
  for (int u2 = 0; u2 < 4; ++u2) {
    loadH(2 * u2 + 1, arB, aiB);
    step(2 * u2, arA, aiA);
    if (u2 < 3) loadH(2 * u2 + 2, arA, aiA);
    step(2 * u2 + 1, arB, aiB);
  }

  // ---- epilogue: noise + magnitude + store (overlaps other waves' K-loops) --
  const float scale = 0.04419417382415922f;  // 1/sqrt(512)
  const float nstd  = 0.01f;
  const size_t obase = ((size_t)b * NC + bm * BM + wm * 64 + fq * 4) * NP
                     + (size_t)bn * BN + wn * 16 + fr;
  float nrv[16], niv[16];
  #pragma unroll
  for (int m = 0; m < 4; ++m)
    #pragma unroll
    for (int r = 0; r < 4; ++r) {
      const size_t idx = obase + (size_t)(m * 16 + r) * NP;
      nrv[m * 4 + r] = nrg[idx];
      niv[m * 4 + r] = nig[idx];
    }
  #pragma unroll
  for (int m = 0; m < 4; ++m)
    #pragma unroll
    for (int r = 0; r < 4; ++r) {
      const size_t idx = obase + (size_t)(m * 16 + r) * NP;
      const float yr = accR[m][r] * scale + nrv[m * 4 + r] * nstd;
      const float yi = accI[m][r] * scale + niv[m * 4 + r] * nstd;
      outg[idx] = sqrtf(yr * yr + yi * yi);
    }
}

extern "C" void kernel_launch(void* const* d_in, const int* in_sizes, int n_in,
                              void* d_out, int out_size, void* d_ws, size_t ws_size,
                              hipStream_t stream) {
  const float* x  = (const float*)d_in[0];
  const float* Hr = (const float*)d_in[1];
  const float* Hi = (const float*)d_in[2];
  const float* nr = (const float*)d_in[3];
  const float* ni = (const float*)d_in[4];
  float* out = (float*)d_out;

  const size_t HN = (size_t)NBATCH * NC * NC;  // 2,097,152 elems per H array

  if (ws_size >= HN * 2 * sizeof(unsigned short)) {
    unsigned short* hperm = (unsigned short*)d_ws;
    hipLaunchKernelGGL(perm_h_kernel, dim3(512), dim3(256), 0, stream, Hr, Hi, hperm);
    hipLaunchKernelGGL((rayleigh_main<1>), dim3(NBATCH * 2 * NBN), dim3(512), 0, stream,
                       x, Hr, Hi, hperm, nr, ni, out);
  } else {
    hipLaunchKernelGGL((rayleigh_main<0>), dim3(NBATCH * 2 * NBN), dim3(512), 0, stream,
                       x, Hr, Hi, (const unsigned short*)nullptr, nr, ni, out);
  }
}

// Round 8
// 111.929 us; speedup vs baseline: 1.1882x; 1.1882x over previous
//
#include <hip/hip_runtime.h>
#include <hip/hip_bf16.h>
#include <math.h>

// out[b,i,p] = sqrt(yr^2+yi^2); yr/yi = (Hr/Hi[b] @ x[b])*scale + noise*0.01
// B=32, C=256, P=3136. Memory-bound (~290MB HBM -> ~47us floor).
// Round-8 = round-6 baseline (H pre-permuted, dense DMA staging) +
//  (1) depth-3 LDS pipeline with raw s_barrier + counted vmcnt(3): stage(t)
//      gets 2 iterations of slack, barriers stop draining in-flight DMA;
//  (2) noise loads moved OUT of the K-loop to the epilogue (no NT-load drain
//      at barriers; desynced waves overlap the noise stream with other
//      waves'/blocks' K-loops).

#define NBATCH 32
#define NC 256
#define NP 3136
#define BM 128
#define BN 64
#define BK 32
#define NBN 49
#define NKI 8          // 256/32 K-steps

typedef __attribute__((ext_vector_type(8))) short short8;
typedef __attribute__((ext_vector_type(4))) float f32x4;

static __device__ __forceinline__ void gload16(const void* g, void* l) {
  __builtin_amdgcn_global_load_lds(
      (const __attribute__((address_space(1))) void*)g,
      (__attribute__((address_space(3))) void*)l, 16, 0, 0);
}

static __device__ __forceinline__ unsigned short bfr(float f) {
  __hip_bfloat16 h = __float2bfloat16(f);   // RNE; pairs into v_cvt_pk_bf16_f32
  return *reinterpret_cast<unsigned short*>(&h);
}

// ---- pre-pass: permute Hr/Hi fp32 -> bf16 ws in LDS-image layout ----
// ws elem idx: (((b2m*8 + kt)*2 + plane)*4096) + fq*1024 + row*8 + e
__global__ __launch_bounds__(256)
void perm_h_kernel(const float* __restrict__ hr, const float* __restrict__ hi,
                   unsigned short* __restrict__ ws)
{
  const int blk   = blockIdx.x;        // b2m*8 + kt  (512 blocks)
  const int kt    = blk & 7;
  const int b2m   = blk >> 3;
  const int plane = threadIdx.x >> 7;  // 0..1
  const int row   = threadIdx.x & 127; // 0..127
  const int b     = b2m >> 1;
  const int bm    = b2m & 1;

  const float* src = (plane ? hi : hr)
      + ((size_t)b * NC + bm * 128 + row) * NC + kt * 32;
  unsigned short* dst = ws + ((size_t)(b2m * 8 + kt) * 2 + plane) * 4096 + row * 8;

  #pragma unroll
  for (int fq = 0; fq < 4; ++fq) {
    const float4 v0 = *reinterpret_cast<const float4*>(src + fq * 8);
    const float4 v1 = *reinterpret_cast<const float4*>(src + fq * 8 + 4);
    union { uint4 v; unsigned short u[8]; } o;
    o.u[0] = bfr(v0.x); o.u[1] = bfr(v0.y); o.u[2] = bfr(v0.z); o.u[3] = bfr(v0.w);
    o.u[4] = bfr(v1.x); o.u[5] = bfr(v1.y); o.u[6] = bfr(v1.z); o.u[7] = bfr(v1.w);
    *reinterpret_cast<uint4*>(dst + fq * 1024) = o.v;
  }
}

// x LDS: fp32 [k 0..31][p 0..63] per buffer, phys 16B-chunk = logical ^
// swz(k>>3) (0 bank conflicts, verified r2-r7). H LDS: bf16 [fq][row][8]
// (2-way = free). Pipeline: depth-3 buffers, one raw s_barrier/iter,
// vmcnt(3) BEFORE the barrier (own stage(t) retired -> barrier -> everyone's).
// FIFO at wait(t): stage(t)[3] | stage(t+1)[3]  -> vmcnt(3); t==NKI-1: vmcnt(0).
// Buffer reuse safe: iter t-1 ds_reads complete before a wave reaches
// barrier(t) (MFMAs consumed them under compiler lgkmcnt); stage(t+2) writes
// the third buffer, never the one being read.
template<int PRE>
__global__ __launch_bounds__(512, 4)
void rayleigh_main(const float* __restrict__ xg,
                   const float* __restrict__ Hrg,
                   const float* __restrict__ Hig,
                   const unsigned short* __restrict__ Hperm,
                   const float* __restrict__ nrg,
                   const float* __restrict__ nig,
                   float* __restrict__ outg)
{
  __shared__ float x_lds[3][BK * BN];            // 3 x 8KB
  __shared__ unsigned short hr_lds[3][4096];     // 3 x 8KB  [fq][row][8]
  __shared__ unsigned short hi_lds[3][4096];     // 3 x 8KB

  // XCD-chunked bijection: 3136 = 8*392. Each XCD owns 4 whole batches.
  const int raw = blockIdx.x;
  const int v   = (raw & 7) * 392 + (raw >> 3);
  const int b   = v / 98;
  const int r2  = v - b * 98;
  const int bm  = r2 / 49;
  const int bn  = r2 - bm * 49;

  const int tid  = threadIdx.x;
  const int lane = tid & 63;
  const int wave = tid >> 6;      // 8 waves: 2(M) x 4(N)
  const int wm   = wave >> 2;
  const int wn   = wave & 3;
  const int fr   = lane & 15;
  const int fq   = lane >> 4;

  const float* xsrc = xg + (size_t)b * NC * NP + (size_t)bn * BN;
  const size_t hrowbase = (size_t)b * NC + bm * BM;
  const size_t hpbase   = (size_t)((b * 2 + bm) * 8);

  // stage one K-tile into buffer `buf`: x 8KB (wave w -> chunk w) + H 16KB
  // (wave w -> 2 contiguous 1KB chunks from permuted ws). 3 vmem ops/wave.
  auto stage = [&](int t, int buf) {
    {
      const int C16 = wave * 64 + lane;          // 16B chunk idx in 8KB x-tile
      const int k   = C16 >> 4;
      const int cp  = C16 & 15;
      const int fqk = k >> 3;
      const int cl  = cp ^ (((fqk & 1) << 2) | (fqk >> 1));
      const float* src = xsrc + (size_t)(t * BK + k) * NP + cl * 4;
      gload16(src, (char*)x_lds[buf] + wave * 1024);
    }
    if constexpr (PRE) {
      #pragma unroll
      for (int i = 0; i < 2; ++i) {
        const int c     = wave * 2 + i;          // 0..15
        const int plane = c >> 3;                // 0=r, 1=i
        const int fqc   = (c >> 1) & 3;
        const int half  = c & 1;
        unsigned short* hl = plane ? hi_lds[buf] : hr_lds[buf];
        const unsigned short* src = Hperm
            + ((hpbase + t) * 2 + plane) * 4096
            + fqc * 1024 + (half * 64 + lane) * 8;   // contiguous per lane
        gload16(src, (char*)hl + fqc * 2048 + half * 1024);
      }
    }
  };

  f32x4 accR[4], accI[4];
  #pragma unroll
  for (int m = 0; m < 4; ++m) {
    accR[m] = (f32x4){0.f, 0.f, 0.f, 0.f};
    accI[m] = (f32x4){0.f, 0.f, 0.f, 0.f};
  }

  const size_t obase = ((size_t)b * NC + bm * BM + wm * 64 + fq * 4) * NP
                     + (size_t)bn * BN + wn * 16 + fr;
  const int xork = ((fq & 1) << 6) | ((fq >> 1) << 4);
  const int pcol = ((wn * 16 + fr) << 2) ^ xork;

  stage(0, 0);
  stage(1, 1);

  for (int t = 0; t < NKI; ++t) {
    const int buf = t % 3;
    if constexpr (PRE) {
      // own stage(t) retired FIRST (stage(t+1) may stay in flight), then
      // barrier => ALL waves' stage(t) landed. Never drains to 0 mid-loop.
      if (t < NKI - 1) asm volatile("s_waitcnt vmcnt(3)" ::: "memory");
      else             asm volatile("s_waitcnt vmcnt(0)" ::: "memory");
      __builtin_amdgcn_s_barrier();
      __builtin_amdgcn_sched_barrier(0);   // rule #18: no LDS-read hoisting
    } else {
      __syncthreads();
    }
    if (t + 2 < NKI) stage(t + 2, (t + 2) % 3);

    // B-fragment: 8 swizzled ds_read_b32 + pk-convert (0 bank conflicts)
    const char* xbuf = (const char*)x_lds[buf];
    union { short8 s; unsigned short u[8]; } u;
    #pragma unroll
    for (int j = 0; j < 8; ++j) {
      const float f = *reinterpret_cast<const float*>(xbuf + ((fq * 8 + j) << 8) + pcol);
      u.u[j] = bfr(f);
    }
    const short8 xb = u.s;

    // A-fragments from LDS (ds_read_b128, 2-way = free) + MFMA
    #pragma unroll
    for (int m = 0; m < 4; ++m) {
      const int row = wm * 64 + m * 16 + fr;
      short8 ar, ai;
      if constexpr (PRE) {
        ar = *reinterpret_cast<const short8*>(&hr_lds[buf][fq * 1024 + row * 8]);
        ai = *reinterpret_cast<const short8*>(&hi_lds[buf][fq * 1024 + row * 8]);
      } else {
        const float* p1 = Hrg + (hrowbase + row) * NC + t * 32 + fq * 8;
        const float* p2 = Hig + (hrowbase + row) * NC + t * 32 + fq * 8;
        const float4 v0 = *reinterpret_cast<const float4*>(p1);
        const float4 v1 = *reinterpret_cast<const float4*>(p1 + 4);
        const float4 w0 = *reinterpret_cast<const float4*>(p2);
        const float4 w1 = *reinterpret_cast<const float4*>(p2 + 4);
        union { short8 s; unsigned short uu[8]; } a1, a2;
        a1.uu[0] = bfr(v0.x); a1.uu[1] = bfr(v0.y); a1.uu[2] = bfr(v0.z); a1.uu[3] = bfr(v0.w);
        a1.uu[4] = bfr(v1.x); a1.uu[5] = bfr(v1.y); a1.uu[6] = bfr(v1.z); a1.uu[7] = bfr(v1.w);
        a2.uu[0] = bfr(w0.x); a2.uu[1] = bfr(w0.y); a2.uu[2] = bfr(w0.z); a2.uu[3] = bfr(w0.w);
        a2.uu[4] = bfr(w1.x); a2.uu[5] = bfr(w1.y); a2.uu[6] = bfr(w1.z); a2.uu[7] = bfr(w1.w);
        ar = a1.s; ai = a2.s;
      }
      accR[m] = __builtin_amdgcn_mfma_f32_16x16x32_bf16(ar, xb, accR[m], 0, 0, 0);
      accI[m] = __builtin_amdgcn_mfma_f32_16x16x32_bf16(ai, xb, accI[m], 0, 0, 0);
    }
  }

  // ---- epilogue: noise (batched plain loads, outside all barriers) +
  //      magnitude + store. Desynced waves overlap this with other K-loops.
  const float scale = 0.04419417382415922f;  // 1/sqrt(512)
  const float nstd  = 0.01f;
  float nrv[16], niv[16];
  #pragma unroll
  for (int m = 0; m < 4; ++m)
    #pragma unroll
    for (int r = 0; r < 4; ++r) {
      const size_t idx = obase + (size_t)(m * 16 + r) * NP;
      nrv[m * 4 + r] = nrg[idx];
      niv[m * 4 + r] = nig[idx];
    }
  #pragma unroll
  for (int m = 0; m < 4; ++m)
    #pragma unroll
    for (int r = 0; r < 4; ++r) {
      const size_t idx = obase + (size_t)(m * 16 + r) * NP;
      const float yr = accR[m][r] * scale + nrv[m * 4 + r] * nstd;
      const float yi = accI[m][r] * scale + niv[m * 4 + r] * nstd;
      outg[idx] = sqrtf(yr * yr + yi * yi);
    }
}

extern "C" void kernel_launch(void* const* d_in, const int* in_sizes, int n_in,
                              void* d_out, int out_size, void* d_ws, size_t ws_size,
                              hipStream_t stream) {
  const float* x  = (const float*)d_in[0];
  const float* Hr = (const float*)d_in[1];
  const float* Hi = (const float*)d_in[2];
  const float* nr = (const float*)d_in[3];
  const float* ni = (const float*)d_in[4];
  float* out = (float*)d_out;

  const size_t HN = (size_t)NBATCH * NC * NC;  // 2,097,152 elems per H array

  if (ws_size >= HN * 2 * sizeof(unsigned short)) {
    unsigned short* hperm = (unsigned short*)d_ws;
    hipLaunchKernelGGL(perm_h_kernel, dim3(512), dim3(256), 0, stream, Hr, Hi, hperm);
    hipLaunchKernelGGL((rayleigh_main<1>), dim3(NBATCH * 2 * NBN), dim3(512), 0, stream,
                       x, Hr, Hi, hperm, nr, ni, out);
  } else {
    hipLaunchKernelGGL((rayleigh_main<0>), dim3(NBATCH * 2 * NBN), dim3(512), 0, stream,
                       x, Hr, Hi, (const unsigned short*)nullptr, nr, ni, out);
  }
}